// Round 7
// baseline (406.310 us; speedup 1.0000x reference)
//
#include <hip/hip_runtime.h>
#include <hip/hip_bf16.h>
#include <math.h>

#define NE 8
#define TOPK 2
#define HD 1024
#define FD 4096
#define NTOK 4096
#define NASSIGN 8192
#define CAP 1024

typedef __attribute__((ext_vector_type(8))) short short8;
typedef __attribute__((ext_vector_type(4))) float f32x4;
typedef __attribute__((ext_vector_type(4))) unsigned short us4;
typedef __attribute__((ext_vector_type(4))) unsigned int u32x4;

__device__ __forceinline__ unsigned short f2bf(float f) {
  unsigned u = __float_as_uint(f);
  u += 0x7fffu + ((u >> 16) & 1u);
  return (unsigned short)(u >> 16);
}

__device__ __forceinline__ void load_lds16(const void* g, void* l) {
  __builtin_amdgcn_global_load_lds((const __attribute__((address_space(1))) void*)g,
                                   (__attribute__((address_space(3))) void*)l, 16, 0, 0);
}

// ---------------- fused transpose + fp32->bf16 for w1 AND w2 ----------------
__global__ __launch_bounds__(256)
void transpose_both(const float* __restrict__ w1, const float* __restrict__ w2,
                    unsigned short* __restrict__ w1t, unsigned short* __restrict__ w2t) {
  __shared__ float tile[64][65];
  int z = blockIdx.z;
  const float* W;
  unsigned short* Wt;
  int R, C, c0, r0;
  if (z < NE) {                       // w1: [HD][FD] -> w1t [FD][HD]
    W = w1 + (size_t)z * HD * FD; Wt = w1t + (size_t)z * HD * FD;
    R = HD; C = FD; c0 = blockIdx.x * 64; r0 = blockIdx.y * 64;
  } else {                            // w2: [FD][HD] -> w2t [HD][FD]
    int e = z - NE;
    W = w2 + (size_t)e * HD * FD; Wt = w2t + (size_t)e * HD * FD;
    R = FD; C = HD; c0 = blockIdx.y * 64; r0 = blockIdx.x * 64;
  }
  int tx = threadIdx.x & 15, ty = threadIdx.x >> 4;
#pragma unroll
  for (int i = 0; i < 4; ++i) {
    f32x4 v = *(const f32x4*)(W + (size_t)(r0 + ty + i * 16) * C + c0 + tx * 4);
    tile[ty + i * 16][tx * 4 + 0] = v.x;
    tile[ty + i * 16][tx * 4 + 1] = v.y;
    tile[ty + i * 16][tx * 4 + 2] = v.z;
    tile[ty + i * 16][tx * 4 + 3] = v.w;
  }
  __syncthreads();
#pragma unroll
  for (int i = 0; i < 4; ++i) {
    int c = ty + i * 16;
    us4 o;
    o.x = f2bf(tile[tx * 4 + 0][c]);
    o.y = f2bf(tile[tx * 4 + 1][c]);
    o.z = f2bf(tile[tx * 4 + 2][c]);
    o.w = f2bf(tile[tx * 4 + 3][c]);
    *(us4*)(Wt + (size_t)(c0 + c) * R + r0 + tx * 4) = o;
  }
}

// ---------------- routing: stable counting sort metadata ----------------
__global__ __launch_bounds__(1024)
void routing_kernel(const int* __restrict__ te, int* __restrict__ rankA,
                    int* __restrict__ srcTok, int* __restrict__ counts) {
  __shared__ uint4 pref[1024];
  int t = threadIdx.x;
  int myTe[8];
  unsigned lc[4] = {0, 0, 0, 0};
#pragma unroll
  for (int j = 0; j < 8; ++j) {
    int ee = te[t * 8 + j];
    myTe[j] = ee;
    lc[ee >> 1] += 1u << ((ee & 1) * 16);
  }
  uint4 inc;
  inc.x = lc[0]; inc.y = lc[1]; inc.z = lc[2]; inc.w = lc[3];
  pref[t] = inc;
  __syncthreads();
  for (int d = 1; d < 1024; d <<= 1) {
    uint4 add;
    bool has = (t >= d);
    if (has) add = pref[t - d];
    __syncthreads();
    if (has) {
      inc.x += add.x; inc.y += add.y; inc.z += add.z; inc.w += add.w;
      pref[t] = inc;
    }
    __syncthreads();
  }
  unsigned ex[4] = {inc.x - lc[0], inc.y - lc[1], inc.z - lc[2], inc.w - lc[3]};
  uint4 tot = pref[1023];
  int run[8];
#pragma unroll
  for (int eidx = 0; eidx < 8; ++eidx)
    run[eidx] = (ex[eidx >> 1] >> ((eidx & 1) * 16)) & 0xffff;
#pragma unroll
  for (int j = 0; j < 8; ++j) {
    int ee = myTe[j];
    int r = run[ee]++;
    rankA[t * 8 + j] = r;
    if (r < CAP) srcTok[ee * CAP + r] = (t * 8 + j) >> 1;
  }
  if (t < 8) {
    unsigned tt[4] = {tot.x, tot.y, tot.z, tot.w};
    counts[t] = (tt[t >> 1] >> ((t & 1) * 16)) & 0xffff;
  }
}

// ---------------- gather x rows into bf16 buf[E][CAP][HD], zero pad ----------------
__global__ __launch_bounds__(128)
void gather_kernel(const float* __restrict__ x, const int* __restrict__ srcTok,
                   const int* __restrict__ counts, unsigned short* __restrict__ buf) {
  int row = blockIdx.x;
  int e = row >> 10;
  int c = row & (CAP - 1);
  int t = threadIdx.x;
  unsigned short* dst = buf + (size_t)row * HD + t * 8;
  if (c < counts[e]) {
    const float* src = x + (size_t)srcTok[row] * HD + t * 8;
    f32x4 v0 = *(const f32x4*)src;
    f32x4 v1 = *(const f32x4*)(src + 4);
    u32x4 o;
    o.x = f2bf(v0.x) | ((unsigned)f2bf(v0.y) << 16);
    o.y = f2bf(v0.z) | ((unsigned)f2bf(v0.w) << 16);
    o.z = f2bf(v1.x) | ((unsigned)f2bf(v1.y) << 16);
    o.w = f2bf(v1.z) | ((unsigned)f2bf(v1.w) << 16);
    *(u32x4*)dst = o;
  } else {
    u32x4 z = {0, 0, 0, 0};
    *(u32x4*)dst = z;
  }
}

// ---------------- 256x256 ring-4 pipelined GEMM, immediate-offset addressing -------
// A[e][CAP][KTOT] bf16 row-major, Bt[e][NDIM][KTOT] bf16 row-major (= B^T).
// C = A @ Bt^T. 8 waves (2Mx4N), per-wave 128x64, BK=32, ring-4 LDS (128KB),
// K-loop unrolled x4 with LITERAL buffer bases -> all ds_reads are
// `ds_read_b128 v, pX offset:imm` (zero VALU); staging offsets fold into the
// 13-bit global-load immediates; register ping-pong read-ahead; exact tail vmcnt.
template <int KTOT, int NDIM, int DO_GELU, int KSPLIT>
__global__ __launch_bounds__(512, 2)
void gemm256(const unsigned short* __restrict__ Ab, const unsigned short* __restrict__ Bb,
             void* __restrict__ Cv) {
  constexpr int KLOC = KTOT / KSPLIT;
  constexpr int NT = KLOC / 32;              // K-tiles, multiple of 4
  constexpr int GX = CAP / 256;
  constexpr int GY = NDIM / 256;
  constexpr int NWG = GX * GY * NE * KSPLIT;
  __shared__ char smem[4 * 32768];           // ring-4: A 16KB + B 16KB per buf

  int orig = blockIdx.x;
  int wg = (orig & 7) * (NWG / 8) + (orig >> 3);   // XCD-aware, NWG%8==0
  int bx = wg % GX;
  int by = (wg / GX) % GY;
  int zz = wg / (GX * GY);
  int ks = zz % KSPLIT;
  int e  = zz / KSPLIT;

  const unsigned short* A  = Ab + (size_t)e * CAP * KTOT;
  const unsigned short* Bt = Bb + (size_t)e * NDIM * KTOT;
  int bm = bx * 256, bn = by * 256;
  int kbase = ks * KLOC;

  int tid = threadIdx.x;
  int lane = tid & 63;
  int w = tid >> 6;
  int wr = w >> 2, wc = w & 3;
  int l15 = lane & 15, lq = lane >> 4;

  // fragment base pointers (swizzle is pure thread-constant; frag idx folds to imm)
  unsigned sw = (unsigned)((lq ^ ((l15 >> 1) & 3)) << 4);
  const char* pA  = smem + (unsigned)((wr * 128 + l15) * 64) + sw;          // bufs 0,1
  const char* pA2 = pA + 65536;                                            // bufs 2,3
  const char* pB  = smem + 16384u + (unsigned)((wc * 64 + l15) * 64) + sw; // bufs 0,1
  const char* pB2 = pB + 65536;                                            // bufs 2,3

  // staging (pre-swizzled global source, linear LDS dest) — proven r2-r4 mapping
  const char *sA0, *sA1, *sB0, *sB1;
  char *dA0, *dA1, *dB0, *dB1;
  {
    int i0 = tid, i1 = 512 + tid;
    int r0_ = i0 >> 2, r1_ = i1 >> 2;
    unsigned kb0 = ((unsigned)(i0 & 3) ^ (((unsigned)r0_ >> 1) & 3u)) << 4;
    unsigned kb1 = ((unsigned)(i1 & 3) ^ (((unsigned)r1_ >> 1) & 3u)) << 4;
    sA0 = (const char*)(A  + (size_t)(bm + r0_) * KTOT + kbase) + kb0;
    sA1 = (const char*)(A  + (size_t)(bm + r1_) * KTOT + kbase) + kb1;
    sB0 = (const char*)(Bt + (size_t)(bn + r0_) * KTOT + kbase) + kb0;
    sB1 = (const char*)(Bt + (size_t)(bn + r1_) * KTOT + kbase) + kb1;
    dA0 = smem + (unsigned)i0 * 16;  dA1 = smem + (unsigned)i1 * 16;
    dB0 = smem + 16384u + (unsigned)i0 * 16; dB1 = smem + 16384u + (unsigned)i1 * 16;
  }

  // prologue: stage tiles 0,1,2 into bufs 0,1,2
#pragma unroll
  for (int tt = 0; tt < 3; ++tt) {
    load_lds16(sA0 + tt * 64, dA0 + tt * 32768);
    load_lds16(sA1 + tt * 64, dA1 + tt * 32768);
    load_lds16(sB0 + tt * 64, dB0 + tt * 32768);
    load_lds16(sB1 + tt * 64, dB1 + tt * 32768);
  }
  asm volatile("s_waitcnt vmcnt(4)" ::: "memory");   // tiles 0,1 landed
  __builtin_amdgcn_s_barrier();

  f32x4 acc[8][4] = {};
  short8 afLo0[4], afLo1[4], bf0[4], bf1[4], af47[4];

  // preload tile0 subtile-lo into set 0 (buf0 = offset 0)
#pragma unroll
  for (int j = 0; j < 4; ++j) afLo0[j] = *(const short8*)(pA + j * 1024);
#pragma unroll
  for (int n = 0; n < 4; ++n) bf0[n]  = *(const short8*)(pB + n * 1024);

  // U: tile index within the 4-unroll (buf = U); CUR/NXT: register ping-pong sets.
  // PAc/PBc: pointer for buf U (pA or pA2); OFFc: 0 or 32768. Same for buf U+1 (read-ahead).
#define TILE(U, CUR, NXT, PAc, OFFc, PAn, OFFn, PBc, PBn)                         \
  {                                                                               \
    const int t_ = t + (U);                                                       \
    _Pragma("unroll") for (int j = 0; j < 4; ++j)                                 \
        af47[j] = *(const short8*)(PAc + (OFFc + (4 + j) * 1024));                \
    if (t_ + 3 < NT) {                                                            \
      load_lds16(sA0 + ((U) + 3) * 64, dA0 + (((U) + 3) & 3) * 32768);            \
      load_lds16(sA1 + ((U) + 3) * 64, dA1 + (((U) + 3) & 3) * 32768);            \
    }                                                                             \
    __builtin_amdgcn_sched_barrier(0);                                            \
    __builtin_amdgcn_s_setprio(1);                                                \
    _Pragma("unroll") for (int m = 0; m < 4; ++m)                                 \
      _Pragma("unroll") for (int n = 0; n < 4; ++n)                               \
        acc[m][n] = __builtin_amdgcn_mfma_f32_16x16x32_bf16(                      \
            afLo##CUR[m], bf##CUR[n], acc[m][n], 0, 0, 0);                        \
    __builtin_amdgcn_s_setprio(0);                                                \
    __builtin_amdgcn_sched_barrier(0);                                            \
    if (t_ + 1 < NT) {                                                            \
      _Pragma("unroll") for (int j = 0; j < 4; ++j)                               \
          afLo##NXT[j] = *(const short8*)(PAn + (OFFn + j * 1024));               \
      _Pragma("unroll") for (int n = 0; n < 4; ++n)                               \
          bf##NXT[n] = *(const short8*)(PBn + (OFFn + n * 1024));                 \
    }                                                                             \
    if (t_ + 3 < NT) {                                                            \
      load_lds16(sB0 + ((U) + 3) * 64, dB0 + (((U) + 3) & 3) * 32768);            \
      load_lds16(sB1 + ((U) + 3) * 64, dB1 + (((U) + 3) & 3) * 32768);            \
    }                                                                             \
    __builtin_amdgcn_sched_barrier(0);                                            \
    __builtin_amdgcn_s_setprio(1);                                                \
    _Pragma("unroll") for (int m = 0; m < 4; ++m)                                 \
      _Pragma("unroll") for (int n = 0; n < 4; ++n)                               \
        acc[m + 4][n] = __builtin_amdgcn_mfma_f32_16x16x32_bf16(                  \
            af47[m], bf##CUR[n], acc[m + 4][n], 0, 0, 0);                         \
    __builtin_amdgcn_s_setprio(0);                                                \
    __builtin_amdgcn_sched_barrier(0);                                            \
    if (t_ + 3 < NT) asm volatile("s_waitcnt vmcnt(4)" ::: "memory");             \
    else             asm volatile("s_waitcnt vmcnt(0)" ::: "memory");             \
    __builtin_amdgcn_s_barrier();                                                 \
  }

#pragma unroll 1
  for (int t = 0; t < NT; t += 4) {
    TILE(0, 0, 1, pA, 0, pA, 32768, pB, pB)       // buf0, next=buf1
    TILE(1, 1, 0, pA, 32768, pA2, 0, pB, pB2)     // buf1, next=buf2
    TILE(2, 0, 1, pA2, 0, pA2, 32768, pB2, pB2)   // buf2, next=buf3
    TILE(3, 1, 0, pA2, 32768, pA, 0, pB2, pB)     // buf3, next=buf0
    sA0 += 256; sA1 += 256; sB0 += 256; sB1 += 256;
  }
#undef TILE

  // epilogue (proven C/D mapping)
  int r0 = bm + wr * 128 + lq * 4;
  int c0 = bn + wc * 64 + l15;
  if (DO_GELU) {
    unsigned short* C = (unsigned short*)Cv + (size_t)e * CAP * NDIM;
#pragma unroll
    for (int m = 0; m < 8; ++m)
#pragma unroll
      for (int n = 0; n < 4; ++n)
#pragma unroll
        for (int j = 0; j < 4; ++j) {
          float v = acc[m][n][j];
          float y = 0.7978845608028654f * (v + 0.044715f * v * v * v);
          float g = v / (1.0f + __expf(-2.0f * y));   // tanh-gelu
          C[(size_t)(r0 + m * 16 + j) * NDIM + (c0 + n * 16)] = f2bf(g);
        }
  } else {
    float* C = (float*)Cv + ((size_t)ks * NE + e) * CAP * NDIM;
#pragma unroll
    for (int m = 0; m < 8; ++m)
#pragma unroll
      for (int n = 0; n < 4; ++n)
#pragma unroll
        for (int j = 0; j < 4; ++j)
          C[(size_t)(r0 + m * 16 + j) * NDIM + (c0 + n * 16)] = acc[m][n][j];
  }
}

// ---------------- scatter: out[t] = sum_k w[t,k]*(y0[e,r]+y1[e,r]) + bias ----------------
__global__ __launch_bounds__(128)
void scatter_kernel(const float* __restrict__ y, const int* __restrict__ te,
                    const int* __restrict__ rankA, const float* __restrict__ ew,
                    const float* __restrict__ bias, float* __restrict__ out) {
  int tk = blockIdx.x;
  int t = threadIdx.x;
  f32x4 a0 = *(const f32x4*)(bias + t * 8);
  f32x4 a1 = *(const f32x4*)(bias + t * 8 + 4);
#pragma unroll
  for (int k = 0; k < TOPK; ++k) {
    int a = tk * TOPK + k;
    int r = rankA[a];
    if (r < CAP) {
      float wgt = ew[a];
      size_t rowoff = ((size_t)te[a] * CAP + r) * HD + t * 8;
      const float* y0 = y + rowoff;
      const float* y1 = y + (size_t)NE * CAP * HD + rowoff;
      f32x4 v0 = *(const f32x4*)y0 + *(const f32x4*)y1;
      f32x4 v1 = *(const f32x4*)(y0 + 4) + *(const f32x4*)(y1 + 4);
      a0 += wgt * v0;
      a1 += wgt * v1;
    }
  }
  float* o = out + (size_t)tk * HD + t * 8;
  *(f32x4*)o = a0;
  *(f32x4*)(o + 4) = a1;
}

extern "C" void kernel_launch(void* const* d_in, const int* in_sizes, int n_in,
                              void* d_out, int out_size, void* d_ws, size_t ws_size,
                              hipStream_t stream) {
  const float* x    = (const float*)d_in[0];
  const float* ew   = (const float*)d_in[2];
  const int*   te   = (const int*)d_in[3];
  const float* w1   = (const float*)d_in[4];
  const float* w2   = (const float*)d_in[5];
  const float* bias = (const float*)d_in[6];
  float* out = (float*)d_out;

  unsigned short* w1t  = (unsigned short*)d_ws;                 // [E][F][H] bf16  64MB
  unsigned short* w2t  = w1t + (size_t)NE * HD * FD;            // [E][H][F] bf16  64MB
  unsigned short* bufg = w2t + (size_t)NE * HD * FD;            // [E][CAP][H]     16MB
  unsigned short* hbuf = bufg + (size_t)NE * CAP * HD;          // [E][CAP][F]     64MB
  float*          ybuf = (float*)w1t;                           // alias (w1t dead after GEMM1)
  int* rankA  = (int*)(hbuf + (size_t)NE * CAP * FD);
  int* srcTok = rankA + NASSIGN;
  int* counts = srcTok + NE * CAP;

  transpose_both<<<dim3(FD / 64, HD / 64, NE * 2), 256, 0, stream>>>(w1, w2, w1t, w2t);
  routing_kernel<<<1, 1024, 0, stream>>>(te, rankA, srcTok, counts);
  gather_kernel<<<NE * CAP, 128, 0, stream>>>(x, srcTok, counts, bufg);
  // GEMM1: [CAP,HD] @ [FD,HD]^T -> gelu -> bf16 hbuf ; 512 blocks
  gemm256<HD, FD, 1, 1><<<512, 512, 0, stream>>>(bufg, w1t, (void*)hbuf);
  // GEMM2: [CAP,FD] @ [HD,FD]^T -> fp32 partials (split-K=2) ; 256 blocks
  gemm256<FD, HD, 0, 2><<<256, 512, 0, stream>>>(hbuf, w2t, (void*)ybuf);
  scatter_kernel<<<NTOK, 128, 0, stream>>>(ybuf, te, rankA, ew, bias, out);
}

// Round 8
// 274.430 us; speedup vs baseline: 1.4806x; 1.4806x over previous
//
#include <hip/hip_runtime.h>
#include <hip/hip_bf16.h>
#include <math.h>

#define NE 8
#define TOPK 2
#define HD 1024
#define FD 4096
#define NTOK 4096
#define NASSIGN 8192
#define CAP 1024

typedef __attribute__((ext_vector_type(8))) short short8;
typedef __attribute__((ext_vector_type(4))) float f32x4;
typedef __attribute__((ext_vector_type(4))) unsigned short us4;
typedef __attribute__((ext_vector_type(4))) unsigned int u32x4;

__device__ __forceinline__ unsigned short f2bf(float f) {
  unsigned u = __float_as_uint(f);
  u += 0x7fffu + ((u >> 16) & 1u);
  return (unsigned short)(u >> 16);
}

__device__ __forceinline__ void load_lds16(const void* g, void* l) {
  __builtin_amdgcn_global_load_lds((const __attribute__((address_space(1))) void*)g,
                                   (__attribute__((address_space(3))) void*)l, 16, 0, 0);
}

// ---------------- fused transpose + fp32->bf16 for w1 AND w2 ----------------
__global__ __launch_bounds__(256)
void transpose_both(const float* __restrict__ w1, const float* __restrict__ w2,
                    unsigned short* __restrict__ w1t, unsigned short* __restrict__ w2t) {
  __shared__ float tile[64][65];
  int z = blockIdx.z;
  const float* W;
  unsigned short* Wt;
  int R, C, c0, r0;
  if (z < NE) {                       // w1: [HD][FD] -> w1t [FD][HD]
    W = w1 + (size_t)z * HD * FD; Wt = w1t + (size_t)z * HD * FD;
    R = HD; C = FD; c0 = blockIdx.x * 64; r0 = blockIdx.y * 64;
  } else {                            // w2: [FD][HD] -> w2t [HD][FD]
    int e = z - NE;
    W = w2 + (size_t)e * HD * FD; Wt = w2t + (size_t)e * HD * FD;
    R = FD; C = HD; c0 = blockIdx.y * 64; r0 = blockIdx.x * 64;
  }
  int tx = threadIdx.x & 15, ty = threadIdx.x >> 4;
#pragma unroll
  for (int i = 0; i < 4; ++i) {
    f32x4 v = *(const f32x4*)(W + (size_t)(r0 + ty + i * 16) * C + c0 + tx * 4);
    tile[ty + i * 16][tx * 4 + 0] = v.x;
    tile[ty + i * 16][tx * 4 + 1] = v.y;
    tile[ty + i * 16][tx * 4 + 2] = v.z;
    tile[ty + i * 16][tx * 4 + 3] = v.w;
  }
  __syncthreads();
#pragma unroll
  for (int i = 0; i < 4; ++i) {
    int c = ty + i * 16;
    us4 o;
    o.x = f2bf(tile[tx * 4 + 0][c]);
    o.y = f2bf(tile[tx * 4 + 1][c]);
    o.z = f2bf(tile[tx * 4 + 2][c]);
    o.w = f2bf(tile[tx * 4 + 3][c]);
    *(us4*)(Wt + (size_t)(c0 + c) * R + r0 + tx * 4) = o;
  }
}

// ---------------- routing: stable counting sort metadata ----------------
__global__ __launch_bounds__(1024)
void routing_kernel(const int* __restrict__ te, int* __restrict__ rankA,
                    int* __restrict__ srcTok, int* __restrict__ counts) {
  __shared__ uint4 pref[1024];
  int t = threadIdx.x;
  int myTe[8];
  unsigned lc[4] = {0, 0, 0, 0};
#pragma unroll
  for (int j = 0; j < 8; ++j) {
    int ee = te[t * 8 + j];
    myTe[j] = ee;
    lc[ee >> 1] += 1u << ((ee & 1) * 16);
  }
  uint4 inc;
  inc.x = lc[0]; inc.y = lc[1]; inc.z = lc[2]; inc.w = lc[3];
  pref[t] = inc;
  __syncthreads();
  for (int d = 1; d < 1024; d <<= 1) {
    uint4 add;
    bool has = (t >= d);
    if (has) add = pref[t - d];
    __syncthreads();
    if (has) {
      inc.x += add.x; inc.y += add.y; inc.z += add.z; inc.w += add.w;
      pref[t] = inc;
    }
    __syncthreads();
  }
  unsigned ex[4] = {inc.x - lc[0], inc.y - lc[1], inc.z - lc[2], inc.w - lc[3]};
  uint4 tot = pref[1023];
  int run[8];
#pragma unroll
  for (int eidx = 0; eidx < 8; ++eidx)
    run[eidx] = (ex[eidx >> 1] >> ((eidx & 1) * 16)) & 0xffff;
#pragma unroll
  for (int j = 0; j < 8; ++j) {
    int ee = myTe[j];
    int r = run[ee]++;
    rankA[t * 8 + j] = r;
    if (r < CAP) srcTok[ee * CAP + r] = (t * 8 + j) >> 1;
  }
  if (t < 8) {
    unsigned tt[4] = {tot.x, tot.y, tot.z, tot.w};
    counts[t] = (tt[t >> 1] >> ((t & 1) * 16)) & 0xffff;
  }
}

// ---------------- gather x rows into bf16 buf[E][CAP][HD], zero pad ----------------
__global__ __launch_bounds__(128)
void gather_kernel(const float* __restrict__ x, const int* __restrict__ srcTok,
                   const int* __restrict__ counts, unsigned short* __restrict__ buf) {
  int row = blockIdx.x;
  int e = row >> 10;
  int c = row & (CAP - 1);
  int t = threadIdx.x;
  unsigned short* dst = buf + (size_t)row * HD + t * 8;
  if (c < counts[e]) {
    const float* src = x + (size_t)srcTok[row] * HD + t * 8;
    f32x4 v0 = *(const f32x4*)src;
    f32x4 v1 = *(const f32x4*)(src + 4);
    u32x4 o;
    o.x = f2bf(v0.x) | ((unsigned)f2bf(v0.y) << 16);
    o.y = f2bf(v0.z) | ((unsigned)f2bf(v0.w) << 16);
    o.z = f2bf(v1.x) | ((unsigned)f2bf(v1.y) << 16);
    o.w = f2bf(v1.z) | ((unsigned)f2bf(v1.w) << 16);
    *(u32x4*)dst = o;
  } else {
    u32x4 z = {0, 0, 0, 0};
    *(u32x4*)dst = z;
  }
}

// ---------------- 256x256 ring-4 GEMM, compiler-scheduled read/MFMA interleave -----
// A[e][CAP][KTOT] bf16 row-major, Bt[e][NDIM][KTOT] bf16 row-major (= B^T).
// C = A @ Bt^T. 8 waves (2Mx4N), per-wave 128x64, BK=32, ring-4 LDS (128KB).
// NO explicit lgkmcnt/sched_barrier/setprio in the compute path: the compiler
// emits counted lgkmcnt between each ds_read and its consuming MFMA, allowing
// LDS-read completion to overlap the MFMA stream. Only counted-vmcnt + barrier
// (memory clobber) per K-tile; exact tail ladder 8/4/0.
template <int KTOT, int NDIM, int DO_GELU, int KSPLIT>
__global__ __launch_bounds__(512, 2)
void gemm256(const unsigned short* __restrict__ Ab, const unsigned short* __restrict__ Bb,
             void* __restrict__ Cv) {
  constexpr int KLOC = KTOT / KSPLIT;
  constexpr int NT = KLOC / 32;              // K-tiles, >= 4
  constexpr int GX = CAP / 256;
  constexpr int GY = NDIM / 256;
  constexpr int NWG = GX * GY * NE * KSPLIT;
  __shared__ char smem[4 * 32768];           // ring-4: A 16KB + B 16KB per buf

  int orig = blockIdx.x;
  int wg = (orig & 7) * (NWG / 8) + (orig >> 3);   // XCD-aware, NWG%8==0
  int bx = wg % GX;
  int by = (wg / GX) % GY;
  int zz = wg / (GX * GY);
  int ks = zz % KSPLIT;
  int e  = zz / KSPLIT;

  const unsigned short* A  = Ab + (size_t)e * CAP * KTOT;
  const unsigned short* Bt = Bb + (size_t)e * NDIM * KTOT;
  int bm = bx * 256, bn = by * 256;
  int kbase = ks * KLOC;

  int tid = threadIdx.x;
  int lane = tid & 63;
  int w = tid >> 6;
  int wr = w >> 2, wc = w & 3;
  int l15 = lane & 15, lq = lane >> 4;

  // swizzled ds_read offsets (proven r2-r4): granule = lq ^ ((row>>1)&3)
  unsigned sw = (unsigned)((lq ^ ((l15 >> 1) & 3)) << 4);
  unsigned aoff[8], boff[4];
#pragma unroll
  for (int m = 0; m < 8; ++m)
    aoff[m] = (unsigned)((wr * 128 + m * 16 + l15) * 64) + sw;
#pragma unroll
  for (int n = 0; n < 4; ++n)
    boff[n] = 16384u + (unsigned)((wc * 64 + n * 16 + l15) * 64) + sw;

  // staging (pre-swizzled global source, linear LDS dest) — proven r2-r4 mapping
  const char *sA0, *sA1, *sB0, *sB1;
  unsigned dA0, dA1, dB0, dB1;
  {
    int i0 = tid, i1 = 512 + tid;
    int r0_ = i0 >> 2, r1_ = i1 >> 2;
    unsigned kb0 = ((unsigned)(i0 & 3) ^ (((unsigned)r0_ >> 1) & 3u)) << 4;
    unsigned kb1 = ((unsigned)(i1 & 3) ^ (((unsigned)r1_ >> 1) & 3u)) << 4;
    sA0 = (const char*)(A  + (size_t)(bm + r0_) * KTOT + kbase) + kb0;
    sA1 = (const char*)(A  + (size_t)(bm + r1_) * KTOT + kbase) + kb1;
    sB0 = (const char*)(Bt + (size_t)(bn + r0_) * KTOT + kbase) + kb0;
    sB1 = (const char*)(Bt + (size_t)(bn + r1_) * KTOT + kbase) + kb1;
    dA0 = (unsigned)i0 * 16;  dA1 = (unsigned)i1 * 16;
    dB0 = 16384u + (unsigned)i0 * 16; dB1 = 16384u + (unsigned)i1 * 16;
  }

  // prologue: stage tiles 0,1,2 into bufs 0,1,2
#pragma unroll
  for (int tt = 0; tt < 3; ++tt) {
    char* db = smem + tt * 32768;
    load_lds16(sA0 + tt * 64, db + dA0);
    load_lds16(sA1 + tt * 64, db + dA1);
    load_lds16(sB0 + tt * 64, db + dB0);
    load_lds16(sB1 + tt * 64, db + dB1);
  }
  sA0 += 192; sA1 += 192; sB0 += 192; sB1 += 192;
  asm volatile("s_waitcnt vmcnt(8)\ns_barrier" ::: "memory");   // tile 0 landed

  f32x4 acc[8][4] = {};

#pragma unroll 1
  for (int t = 0; t < NT; ++t) {
    const char* rb = smem + (t & 3) * 32768;
    short8 af[8], bf[4];
#pragma unroll
    for (int n = 0; n < 4; ++n) bf[n] = *(const short8*)(rb + boff[n]);
#pragma unroll
    for (int m = 0; m < 8; ++m) af[m] = *(const short8*)(rb + aoff[m]);
    if (t + 3 < NT) {                          // stage tile t+3 -> buf (t+3)&3
      char* db = smem + ((t + 3) & 3) * 32768;
      load_lds16(sA0, db + dA0);
      load_lds16(sA1, db + dA1);
      load_lds16(sB0, db + dB0);
      load_lds16(sB1, db + dB1);
      sA0 += 64; sA1 += 64; sB0 += 64; sB1 += 64;
    }
    // no lgkmcnt/sched_barrier: compiler inserts counted lgkmcnt per MFMA dep,
    // interleaving MFMA issue with LDS-read completion.
#pragma unroll
    for (int m = 0; m < 8; ++m)
#pragma unroll
      for (int n = 0; n < 4; ++n)
        acc[m][n] = __builtin_amdgcn_mfma_f32_16x16x32_bf16(af[m], bf[n], acc[m][n], 0, 0, 0);
    // buffer-rotation safety: tile t+1's stage must be complete before next iter.
    if (t + 3 < NT)       asm volatile("s_waitcnt vmcnt(8)" ::: "memory");
    else if (t == NT - 3) asm volatile("s_waitcnt vmcnt(4)" ::: "memory");
    else if (t == NT - 2) asm volatile("s_waitcnt vmcnt(0)" ::: "memory");
    asm volatile("s_barrier" ::: "memory");
  }

  // epilogue (proven C/D mapping)
  int r0 = bm + wr * 128 + lq * 4;
  int c0 = bn + wc * 64 + l15;
  if (DO_GELU) {
    unsigned short* C = (unsigned short*)Cv + (size_t)e * CAP * NDIM;
#pragma unroll
    for (int m = 0; m < 8; ++m)
#pragma unroll
      for (int n = 0; n < 4; ++n)
#pragma unroll
        for (int j = 0; j < 4; ++j) {
          float v = acc[m][n][j];
          float y = 0.7978845608028654f * (v + 0.044715f * v * v * v);
          float g = v / (1.0f + __expf(-2.0f * y));   // tanh-gelu
          C[(size_t)(r0 + m * 16 + j) * NDIM + (c0 + n * 16)] = f2bf(g);
        }
  } else {
    float* C = (float*)Cv + ((size_t)ks * NE + e) * CAP * NDIM;
#pragma unroll
    for (int m = 0; m < 8; ++m)
#pragma unroll
      for (int n = 0; n < 4; ++n)
#pragma unroll
        for (int j = 0; j < 4; ++j)
          C[(size_t)(r0 + m * 16 + j) * NDIM + (c0 + n * 16)] = acc[m][n][j];
  }
}

// ---------------- scatter: out[t] = sum_k w[t,k]*(y0[e,r]+y1[e,r]) + bias ----------------
__global__ __launch_bounds__(128)
void scatter_kernel(const float* __restrict__ y, const int* __restrict__ te,
                    const int* __restrict__ rankA, const float* __restrict__ ew,
                    const float* __restrict__ bias, float* __restrict__ out) {
  int tk = blockIdx.x;
  int t = threadIdx.x;
  f32x4 a0 = *(const f32x4*)(bias + t * 8);
  f32x4 a1 = *(const f32x4*)(bias + t * 8 + 4);
#pragma unroll
  for (int k = 0; k < TOPK; ++k) {
    int a = tk * TOPK + k;
    int r = rankA[a];
    if (r < CAP) {
      float wgt = ew[a];
      size_t rowoff = ((size_t)te[a] * CAP + r) * HD + t * 8;
      const float* y0 = y + rowoff;
      const float* y1 = y + (size_t)NE * CAP * HD + rowoff;
      f32x4 v0 = *(const f32x4*)y0 + *(const f32x4*)y1;
      f32x4 v1 = *(const f32x4*)(y0 + 4) + *(const f32x4*)(y1 + 4);
      a0 += wgt * v0;
      a1 += wgt * v1;
    }
  }
  float* o = out + (size_t)tk * HD + t * 8;
  *(f32x4*)o = a0;
  *(f32x4*)(o + 4) = a1;
}

extern "C" void kernel_launch(void* const* d_in, const int* in_sizes, int n_in,
                              void* d_out, int out_size, void* d_ws, size_t ws_size,
                              hipStream_t stream) {
  const float* x    = (const float*)d_in[0];
  const float* ew   = (const float*)d_in[2];
  const int*   te   = (const int*)d_in[3];
  const float* w1   = (const float*)d_in[4];
  const float* w2   = (const float*)d_in[5];
  const float* bias = (const float*)d_in[6];
  float* out = (float*)d_out;

  unsigned short* w1t  = (unsigned short*)d_ws;                 // [E][F][H] bf16  64MB
  unsigned short* w2t  = w1t + (size_t)NE * HD * FD;            // [E][H][F] bf16  64MB
  unsigned short* bufg = w2t + (size_t)NE * HD * FD;            // [E][CAP][H]     16MB
  unsigned short* hbuf = bufg + (size_t)NE * CAP * HD;          // [E][CAP][F]     64MB
  float*          ybuf = (float*)w1t;                           // alias (w1t dead after GEMM1)
  int* rankA  = (int*)(hbuf + (size_t)NE * CAP * FD);
  int* srcTok = rankA + NASSIGN;
  int* counts = srcTok + NE * CAP;

  transpose_both<<<dim3(FD / 64, HD / 64, NE * 2), 256, 0, stream>>>(w1, w2, w1t, w2t);
  routing_kernel<<<1, 1024, 0, stream>>>(te, rankA, srcTok, counts);
  gather_kernel<<<NE * CAP, 128, 0, stream>>>(x, srcTok, counts, bufg);
  // GEMM1: [CAP,HD] @ [FD,HD]^T -> gelu -> bf16 hbuf ; 512 blocks
  gemm256<HD, FD, 1, 1><<<512, 512, 0, stream>>>(bufg, w1t, (void*)hbuf);
  // GEMM2: [CAP,FD] @ [HD,FD]^T -> fp32 partials (split-K=2) ; 256 blocks
  gemm256<FD, HD, 0, 2><<<256, 512, 0, stream>>>(hbuf, w2t, (void*)ybuf);
  scatter_kernel<<<NTOK, 128, 0, stream>>>(ybuf, te, rankA, ew, bias, out);
}

// Round 9
// 268.262 us; speedup vs baseline: 1.5146x; 1.0230x over previous
//
#include <hip/hip_runtime.h>
#include <hip/hip_bf16.h>
#include <math.h>

#define NE 8
#define TOPK 2
#define HD 1024
#define FD 4096
#define NTOK 4096
#define NASSIGN 8192
#define CAP 1024

typedef __attribute__((ext_vector_type(8))) short short8;
typedef __attribute__((ext_vector_type(4))) float f32x4;
typedef __attribute__((ext_vector_type(4))) unsigned short us4;
typedef __attribute__((ext_vector_type(4))) unsigned int u32x4;

__device__ __forceinline__ unsigned short f2bf(float f) {
  unsigned u = __float_as_uint(f);
  u += 0x7fffu + ((u >> 16) & 1u);
  return (unsigned short)(u >> 16);
}

__device__ __forceinline__ void load_lds16(const void* g, void* l) {
  __builtin_amdgcn_global_load_lds((const __attribute__((address_space(1))) void*)g,
                                   (__attribute__((address_space(3))) void*)l, 16, 0, 0);
}

// ---------------- transpose + fp32->bf16 convert: W[R][C] -> Wt[C][R] ----------------
// (r1-r4 proven form: ~6 TB/s; do NOT fuse/reorder — r8 showed the fused variant
//  drops to 2.4 TB/s from lost read locality.)
__global__ __launch_bounds__(256)
void transpose_convert(const float* __restrict__ W, unsigned short* __restrict__ Wt,
                       int R, int C) {
  __shared__ float tile[64][65];
  int e = blockIdx.z;
  W  += (size_t)e * R * C;
  Wt += (size_t)e * R * C;
  int c0 = blockIdx.x * 64, r0 = blockIdx.y * 64;
  int tx = threadIdx.x & 15, ty = threadIdx.x >> 4;
#pragma unroll
  for (int i = 0; i < 4; ++i) {
    f32x4 v = *(const f32x4*)(W + (size_t)(r0 + ty + i * 16) * C + c0 + tx * 4);
    tile[ty + i * 16][tx * 4 + 0] = v.x;
    tile[ty + i * 16][tx * 4 + 1] = v.y;
    tile[ty + i * 16][tx * 4 + 2] = v.z;
    tile[ty + i * 16][tx * 4 + 3] = v.w;
  }
  __syncthreads();
#pragma unroll
  for (int i = 0; i < 4; ++i) {
    int c = ty + i * 16;
    us4 o;
    o.x = f2bf(tile[tx * 4 + 0][c]);
    o.y = f2bf(tile[tx * 4 + 1][c]);
    o.z = f2bf(tile[tx * 4 + 2][c]);
    o.w = f2bf(tile[tx * 4 + 3][c]);
    *(us4*)(Wt + (size_t)(c0 + c) * R + r0 + tx * 4) = o;
  }
}

// ---------------- routing: stable counting sort metadata ----------------
__global__ __launch_bounds__(1024)
void routing_kernel(const int* __restrict__ te, int* __restrict__ rankA,
                    int* __restrict__ srcTok, int* __restrict__ counts) {
  __shared__ uint4 pref[1024];
  int t = threadIdx.x;
  int myTe[8];
  unsigned lc[4] = {0, 0, 0, 0};
#pragma unroll
  for (int j = 0; j < 8; ++j) {
    int ee = te[t * 8 + j];
    myTe[j] = ee;
    lc[ee >> 1] += 1u << ((ee & 1) * 16);
  }
  uint4 inc;
  inc.x = lc[0]; inc.y = lc[1]; inc.z = lc[2]; inc.w = lc[3];
  pref[t] = inc;
  __syncthreads();
  for (int d = 1; d < 1024; d <<= 1) {
    uint4 add;
    bool has = (t >= d);
    if (has) add = pref[t - d];
    __syncthreads();
    if (has) {
      inc.x += add.x; inc.y += add.y; inc.z += add.z; inc.w += add.w;
      pref[t] = inc;
    }
    __syncthreads();
  }
  unsigned ex[4] = {inc.x - lc[0], inc.y - lc[1], inc.z - lc[2], inc.w - lc[3]};
  uint4 tot = pref[1023];
  int run[8];
#pragma unroll
  for (int eidx = 0; eidx < 8; ++eidx)
    run[eidx] = (ex[eidx >> 1] >> ((eidx & 1) * 16)) & 0xffff;
#pragma unroll
  for (int j = 0; j < 8; ++j) {
    int ee = myTe[j];
    int r = run[ee]++;
    rankA[t * 8 + j] = r;
    if (r < CAP) srcTok[ee * CAP + r] = (t * 8 + j) >> 1;
  }
  if (t < 8) {
    unsigned tt[4] = {tot.x, tot.y, tot.z, tot.w};
    counts[t] = (tt[t >> 1] >> ((t & 1) * 16)) & 0xffff;
  }
}

// ---------------- gather x rows into bf16 buf[E][CAP][HD], zero pad ----------------
__global__ __launch_bounds__(128)
void gather_kernel(const float* __restrict__ x, const int* __restrict__ srcTok,
                   const int* __restrict__ counts, unsigned short* __restrict__ buf) {
  int row = blockIdx.x;
  int e = row >> 10;
  int c = row & (CAP - 1);
  int t = threadIdx.x;
  unsigned short* dst = buf + (size_t)row * HD + t * 8;
  if (c < counts[e]) {
    const float* src = x + (size_t)srcTok[row] * HD + t * 8;
    f32x4 v0 = *(const f32x4*)src;
    f32x4 v1 = *(const f32x4*)(src + 4);
    u32x4 o;
    o.x = f2bf(v0.x) | ((unsigned)f2bf(v0.y) << 16);
    o.y = f2bf(v0.z) | ((unsigned)f2bf(v0.w) << 16);
    o.z = f2bf(v1.x) | ((unsigned)f2bf(v1.y) << 16);
    o.w = f2bf(v1.z) | ((unsigned)f2bf(v1.w) << 16);
    *(u32x4*)dst = o;
  } else {
    u32x4 z = {0, 0, 0, 0};
    *(u32x4*)dst = z;
  }
}

// ---------------- 256x256 ring-4 GEMM, compiler-scheduled read/MFMA interleave -----
// A[e][CAP][KTOT] bf16 row-major, Bt[e][NDIM][KTOT] bf16 row-major (= B^T).
// C = A @ Bt^T. 8 waves (2Mx4N), per-wave 128x64, BK=32, ring-4 LDS (128KB).
// NO explicit lgkmcnt/sched_barrier/setprio in the compute path (r8: +19%):
// compiler emits counted lgkmcnt per MFMA dep, overlapping LDS-read completion
// with MFMA issue. Counted vmcnt + barrier per K-tile; exact tail ladder 8/4/0.
// OMODE: 1 = gelu->bf16, 2 = plain bf16 (split-K partials).
template <int KTOT, int NDIM, int OMODE, int KSPLIT>
__global__ __launch_bounds__(512, 2)
void gemm256(const unsigned short* __restrict__ Ab, const unsigned short* __restrict__ Bb,
             void* __restrict__ Cv) {
  constexpr int KLOC = KTOT / KSPLIT;
  constexpr int NT = KLOC / 32;              // K-tiles, >= 4
  constexpr int GX = CAP / 256;
  constexpr int GY = NDIM / 256;
  constexpr int NWG = GX * GY * NE * KSPLIT;
  __shared__ char smem[4 * 32768];           // ring-4: A 16KB + B 16KB per buf

  int orig = blockIdx.x;
  int wg = (orig & 7) * (NWG / 8) + (orig >> 3);   // XCD-aware, NWG%8==0
  int bx = wg % GX;
  int by = (wg / GX) % GY;
  int zz = wg / (GX * GY);
  int ks = zz % KSPLIT;
  int e  = zz / KSPLIT;

  const unsigned short* A  = Ab + (size_t)e * CAP * KTOT;
  const unsigned short* Bt = Bb + (size_t)e * NDIM * KTOT;
  int bm = bx * 256, bn = by * 256;
  int kbase = ks * KLOC;

  int tid = threadIdx.x;
  int lane = tid & 63;
  int w = tid >> 6;
  int wr = w >> 2, wc = w & 3;
  int l15 = lane & 15, lq = lane >> 4;

  // swizzled ds_read offsets (proven r2-r4): granule = lq ^ ((row>>1)&3)
  unsigned sw = (unsigned)((lq ^ ((l15 >> 1) & 3)) << 4);
  unsigned aoff[8], boff[4];
#pragma unroll
  for (int m = 0; m < 8; ++m)
    aoff[m] = (unsigned)((wr * 128 + m * 16 + l15) * 64) + sw;
#pragma unroll
  for (int n = 0; n < 4; ++n)
    boff[n] = 16384u + (unsigned)((wc * 64 + n * 16 + l15) * 64) + sw;

  // staging (pre-swizzled global source, linear LDS dest) — proven r2-r4 mapping
  const char *sA0, *sA1, *sB0, *sB1;
  unsigned dA0, dA1, dB0, dB1;
  {
    int i0 = tid, i1 = 512 + tid;
    int r0_ = i0 >> 2, r1_ = i1 >> 2;
    unsigned kb0 = ((unsigned)(i0 & 3) ^ (((unsigned)r0_ >> 1) & 3u)) << 4;
    unsigned kb1 = ((unsigned)(i1 & 3) ^ (((unsigned)r1_ >> 1) & 3u)) << 4;
    sA0 = (const char*)(A  + (size_t)(bm + r0_) * KTOT + kbase) + kb0;
    sA1 = (const char*)(A  + (size_t)(bm + r1_) * KTOT + kbase) + kb1;
    sB0 = (const char*)(Bt + (size_t)(bn + r0_) * KTOT + kbase) + kb0;
    sB1 = (const char*)(Bt + (size_t)(bn + r1_) * KTOT + kbase) + kb1;
    dA0 = (unsigned)i0 * 16;  dA1 = (unsigned)i1 * 16;
    dB0 = 16384u + (unsigned)i0 * 16; dB1 = 16384u + (unsigned)i1 * 16;
  }

  // prologue: stage tiles 0,1,2 into bufs 0,1,2
#pragma unroll
  for (int tt = 0; tt < 3; ++tt) {
    char* db = smem + tt * 32768;
    load_lds16(sA0 + tt * 64, db + dA0);
    load_lds16(sA1 + tt * 64, db + dA1);
    load_lds16(sB0 + tt * 64, db + dB0);
    load_lds16(sB1 + tt * 64, db + dB1);
  }
  sA0 += 192; sA1 += 192; sB0 += 192; sB1 += 192;
  asm volatile("s_waitcnt vmcnt(8)\ns_barrier" ::: "memory");   // tile 0 landed

  f32x4 acc[8][4] = {};

#pragma unroll 1
  for (int t = 0; t < NT; ++t) {
    const char* rb = smem + (t & 3) * 32768;
    short8 af[8], bf[4];
#pragma unroll
    for (int n = 0; n < 4; ++n) bf[n] = *(const short8*)(rb + boff[n]);
#pragma unroll
    for (int m = 0; m < 8; ++m) af[m] = *(const short8*)(rb + aoff[m]);
    if (t + 3 < NT) {                          // stage tile t+3 -> buf (t+3)&3
      char* db = smem + ((t + 3) & 3) * 32768;
      load_lds16(sA0, db + dA0);
      load_lds16(sA1, db + dA1);
      load_lds16(sB0, db + dB0);
      load_lds16(sB1, db + dB1);
      sA0 += 64; sA1 += 64; sB0 += 64; sB1 += 64;
    }
    // no lgkmcnt/sched_barrier: compiler inserts counted lgkmcnt per MFMA dep.
#pragma unroll
    for (int m = 0; m < 8; ++m)
#pragma unroll
      for (int n = 0; n < 4; ++n)
        acc[m][n] = __builtin_amdgcn_mfma_f32_16x16x32_bf16(af[m], bf[n], acc[m][n], 0, 0, 0);
    // buffer-rotation safety: tile t+1's stage must be complete before next iter.
    if (t + 3 < NT)       asm volatile("s_waitcnt vmcnt(8)" ::: "memory");
    else if (t == NT - 3) asm volatile("s_waitcnt vmcnt(4)" ::: "memory");
    else if (t == NT - 2) asm volatile("s_waitcnt vmcnt(0)" ::: "memory");
    asm volatile("s_barrier" ::: "memory");
  }

  // epilogue (proven C/D mapping)
  int r0 = bm + wr * 128 + lq * 4;
  int c0 = bn + wc * 64 + l15;
  if (OMODE == 1) {
    unsigned short* C = (unsigned short*)Cv + (size_t)e * CAP * NDIM;
#pragma unroll
    for (int m = 0; m < 8; ++m)
#pragma unroll
      for (int n = 0; n < 4; ++n)
#pragma unroll
        for (int j = 0; j < 4; ++j) {
          float v = acc[m][n][j];
          float y = 0.7978845608028654f * (v + 0.044715f * v * v * v);
          float g = v / (1.0f + __expf(-2.0f * y));   // tanh-gelu
          C[(size_t)(r0 + m * 16 + j) * NDIM + (c0 + n * 16)] = f2bf(g);
        }
  } else {
    unsigned short* C = (unsigned short*)Cv + ((size_t)ks * NE + e) * CAP * NDIM;
#pragma unroll
    for (int m = 0; m < 8; ++m)
#pragma unroll
      for (int n = 0; n < 4; ++n)
#pragma unroll
        for (int j = 0; j < 4; ++j)
          C[(size_t)(r0 + m * 16 + j) * NDIM + (c0 + n * 16)] = f2bf(acc[m][n][j]);
  }
}

// ---- scatter: out[t] = sum_k w[t,k]*(y0[e,r]+y1[e,r]) + bias ; y is bf16 partials ----
__global__ __launch_bounds__(128)
void scatter_kernel(const unsigned short* __restrict__ y, const int* __restrict__ te,
                    const int* __restrict__ rankA, const float* __restrict__ ew,
                    const float* __restrict__ bias, float* __restrict__ out) {
  int tk = blockIdx.x;
  int t = threadIdx.x;
  f32x4 a0 = *(const f32x4*)(bias + t * 8);
  f32x4 a1 = *(const f32x4*)(bias + t * 8 + 4);
#pragma unroll
  for (int k = 0; k < TOPK; ++k) {
    int a = tk * TOPK + k;
    int r = rankA[a];
    if (r < CAP) {
      float wgt = ew[a];
      size_t rowoff = ((size_t)te[a] * CAP + r) * HD + t * 8;
      u32x4 p0 = *(const u32x4*)(y + rowoff);
      u32x4 p1 = *(const u32x4*)(y + (size_t)NE * CAP * HD + rowoff);
#pragma unroll
      for (int j = 0; j < 2; ++j) {
        unsigned u0 = p0[j], u1 = p1[j];
        a0[2 * j]     += wgt * (__uint_as_float(u0 << 16) + __uint_as_float(u1 << 16));
        a0[2 * j + 1] += wgt * (__uint_as_float(u0 & 0xffff0000u) + __uint_as_float(u1 & 0xffff0000u));
      }
#pragma unroll
      for (int j = 0; j < 2; ++j) {
        unsigned u0 = p0[2 + j], u1 = p1[2 + j];
        a1[2 * j]     += wgt * (__uint_as_float(u0 << 16) + __uint_as_float(u1 << 16));
        a1[2 * j + 1] += wgt * (__uint_as_float(u0 & 0xffff0000u) + __uint_as_float(u1 & 0xffff0000u));
      }
    }
  }
  float* o = out + (size_t)tk * HD + t * 8;
  *(f32x4*)o = a0;
  *(f32x4*)(o + 4) = a1;
}

extern "C" void kernel_launch(void* const* d_in, const int* in_sizes, int n_in,
                              void* d_out, int out_size, void* d_ws, size_t ws_size,
                              hipStream_t stream) {
  const float* x    = (const float*)d_in[0];
  const float* ew   = (const float*)d_in[2];
  const int*   te   = (const int*)d_in[3];
  const float* w1   = (const float*)d_in[4];
  const float* w2   = (const float*)d_in[5];
  const float* bias = (const float*)d_in[6];
  float* out = (float*)d_out;

  unsigned short* w1t  = (unsigned short*)d_ws;                 // [E][F][H] bf16  64MB
  unsigned short* w2t  = w1t + (size_t)NE * HD * FD;            // [E][H][F] bf16  64MB
  unsigned short* bufg = w2t + (size_t)NE * HD * FD;            // [E][CAP][H]     16MB
  unsigned short* hbuf = bufg + (size_t)NE * CAP * HD;          // [E][CAP][F]     64MB
  unsigned short* ybuf = w1t;                                   // alias (w1t dead): [2][E][CAP][H] bf16 32MB
  int* rankA  = (int*)(hbuf + (size_t)NE * CAP * FD);
  int* srcTok = rankA + NASSIGN;
  int* counts = srcTok + NE * CAP;

  transpose_convert<<<dim3(FD / 64, HD / 64, NE), 256, 0, stream>>>(w1, w1t, HD, FD);
  transpose_convert<<<dim3(HD / 64, FD / 64, NE), 256, 0, stream>>>(w2, w2t, FD, HD);
  routing_kernel<<<1, 1024, 0, stream>>>(te, rankA, srcTok, counts);
  gather_kernel<<<NE * CAP, 128, 0, stream>>>(x, srcTok, counts, bufg);
  // GEMM1: [CAP,HD] @ [FD,HD]^T -> gelu -> bf16 hbuf ; 512 blocks
  gemm256<HD, FD, 1, 1><<<512, 512, 0, stream>>>(bufg, w1t, (void*)hbuf);
  // GEMM2: [CAP,FD] @ [HD,FD]^T -> bf16 partials (split-K=2) ; 256 blocks
  gemm256<FD, HD, 2, 2><<<256, 512, 0, stream>>>(hbuf, w2t, (void*)ybuf);
  scatter_kernel<<<NTOK, 128, 0, stream>>>(ybuf, te, rankA, ew, bias, out);
}

// Round 10
// 256.270 us; speedup vs baseline: 1.5855x; 1.0468x over previous
//
#include <hip/hip_runtime.h>
#include <hip/hip_bf16.h>
#include <math.h>

#define NE 8
#define TOPK 2
#define HD 1024
#define FD 4096
#define NTOK 4096
#define NASSIGN 8192
#define CAP 1024

typedef __attribute__((ext_vector_type(8))) short short8;
typedef __attribute__((ext_vector_type(4))) float f32x4;
typedef __attribute__((ext_vector_type(4))) unsigned short us4;
typedef __attribute__((ext_vector_type(4))) unsigned int u32x4;

__device__ __forceinline__ unsigned short f2bf(float f) {
  unsigned u = __float_as_uint(f);
  u += 0x7fffu + ((u >> 16) & 1u);
  return (unsigned short)(u >> 16);
}

__device__ __forceinline__ void load_lds16(const void* g, void* l) {
  __builtin_amdgcn_global_load_lds((const __attribute__((address_space(1))) void*)g,
                                   (__attribute__((address_space(3))) void*)l, 16, 0, 0);
}

// XOR swizzle (proven r2-r4): permute 16B granules by (row>>1)&3; involution.
__device__ __forceinline__ unsigned swz(unsigned b) {
  return b ^ (((b >> 7) & 3u) << 4);
}

// ---------------- transpose + fp32->bf16 convert: W[R][C] -> Wt[C][R] ----------------
// r1-form, ~6 TB/s. Do NOT fuse or reorder the grid mapping (r8 regression).
__global__ __launch_bounds__(256)
void transpose_convert(const float* __restrict__ W, unsigned short* __restrict__ Wt,
                       int R, int C) {
  __shared__ float tile[64][65];
  int e = blockIdx.z;
  W  += (size_t)e * R * C;
  Wt += (size_t)e * R * C;
  int c0 = blockIdx.x * 64, r0 = blockIdx.y * 64;
  int tx = threadIdx.x & 15, ty = threadIdx.x >> 4;
#pragma unroll
  for (int i = 0; i < 4; ++i) {
    f32x4 v = *(const f32x4*)(W + (size_t)(r0 + ty + i * 16) * C + c0 + tx * 4);
    tile[ty + i * 16][tx * 4 + 0] = v.x;
    tile[ty + i * 16][tx * 4 + 1] = v.y;
    tile[ty + i * 16][tx * 4 + 2] = v.z;
    tile[ty + i * 16][tx * 4 + 3] = v.w;
  }
  __syncthreads();
#pragma unroll
  for (int i = 0; i < 4; ++i) {
    int c = ty + i * 16;
    us4 o;
    o.x = f2bf(tile[tx * 4 + 0][c]);
    o.y = f2bf(tile[tx * 4 + 1][c]);
    o.z = f2bf(tile[tx * 4 + 2][c]);
    o.w = f2bf(tile[tx * 4 + 3][c]);
    *(us4*)(Wt + (size_t)(c0 + c) * R + r0 + tx * 4) = o;
  }
}

// ---------------- routing: stable counting sort metadata ----------------
__global__ __launch_bounds__(1024)
void routing_kernel(const int* __restrict__ te, int* __restrict__ rankA,
                    int* __restrict__ srcTok, int* __restrict__ counts) {
  __shared__ uint4 pref[1024];
  int t = threadIdx.x;
  int myTe[8];
  unsigned lc[4] = {0, 0, 0, 0};
#pragma unroll
  for (int j = 0; j < 8; ++j) {
    int ee = te[t * 8 + j];
    myTe[j] = ee;
    lc[ee >> 1] += 1u << ((ee & 1) * 16);
  }
  uint4 inc;
  inc.x = lc[0]; inc.y = lc[1]; inc.z = lc[2]; inc.w = lc[3];
  pref[t] = inc;
  __syncthreads();
  for (int d = 1; d < 1024; d <<= 1) {
    uint4 add;
    bool has = (t >= d);
    if (has) add = pref[t - d];
    __syncthreads();
    if (has) {
      inc.x += add.x; inc.y += add.y; inc.z += add.z; inc.w += add.w;
      pref[t] = inc;
    }
    __syncthreads();
  }
  unsigned ex[4] = {inc.x - lc[0], inc.y - lc[1], inc.z - lc[2], inc.w - lc[3]};
  uint4 tot = pref[1023];
  int run[8];
#pragma unroll
  for (int eidx = 0; eidx < 8; ++eidx)
    run[eidx] = (ex[eidx >> 1] >> ((eidx & 1) * 16)) & 0xffff;
#pragma unroll
  for (int j = 0; j < 8; ++j) {
    int ee = myTe[j];
    int r = run[ee]++;
    rankA[t * 8 + j] = r;
    if (r < CAP) srcTok[ee * CAP + r] = (t * 8 + j) >> 1;
  }
  if (t < 8) {
    unsigned tt[4] = {tot.x, tot.y, tot.z, tot.w};
    counts[t] = (tt[t >> 1] >> ((t & 1) * 16)) & 0xffff;
  }
}

// ---------------- gather x rows into bf16 buf[E][CAP][HD], zero pad ----------------
__global__ __launch_bounds__(128)
void gather_kernel(const float* __restrict__ x, const int* __restrict__ srcTok,
                   const int* __restrict__ counts, unsigned short* __restrict__ buf) {
  int row = blockIdx.x;
  int e = row >> 10;
  int c = row & (CAP - 1);
  int t = threadIdx.x;
  unsigned short* dst = buf + (size_t)row * HD + t * 8;
  if (c < counts[e]) {
    const float* src = x + (size_t)srcTok[row] * HD + t * 8;
    f32x4 v0 = *(const f32x4*)src;
    f32x4 v1 = *(const f32x4*)(src + 4);
    u32x4 o;
    o.x = f2bf(v0.x) | ((unsigned)f2bf(v0.y) << 16);
    o.y = f2bf(v0.z) | ((unsigned)f2bf(v0.w) << 16);
    o.z = f2bf(v1.x) | ((unsigned)f2bf(v1.y) << 16);
    o.w = f2bf(v1.z) | ((unsigned)f2bf(v1.w) << 16);
    *(u32x4*)dst = o;
  } else {
    u32x4 z = {0, 0, 0, 0};
    *(u32x4*)dst = z;
  }
}

// ---------------- 256x256 ring-4 software-pipelined batched GEMM (r4 verbatim) -------
// A[e][CAP][KTOT] bf16 row-major, Bt[e][NDIM][KTOT] bf16 row-major (= B^T).
// C = A @ Bt^T. 8 waves (2Mx4N), per-wave 128x64, BK=32, 4 LDS buffers (128KB).
// Per K-tile: 2 phases with register ping-pong read-ahead, 1 barrier, vmcnt(4).
// Measured best GEMM loop (88 us, r4). OMODE: 1 = gelu->bf16, 2 = bf16 partials.
template <int KTOT, int NDIM, int OMODE, int KSPLIT>
__global__ __launch_bounds__(512, 2)
void gemm256(const unsigned short* __restrict__ Ab, const unsigned short* __restrict__ Bb,
             void* __restrict__ Cv) {
  constexpr int KLOC = KTOT / KSPLIT;
  constexpr int NT = KLOC / 32;              // K-tiles (even, >= 4)
  constexpr int GX = CAP / 256;
  constexpr int GY = NDIM / 256;
  constexpr int NWG = GX * GY * NE * KSPLIT;
  __shared__ char smem[4 * 32768];           // ring-4: per buf A 16KB + B 16KB

  int orig = blockIdx.x;
  int wg = (orig & 7) * (NWG / 8) + (orig >> 3);   // XCD-aware, NWG%8==0
  int bx = wg % GX;
  int by = (wg / GX) % GY;
  int zz = wg / (GX * GY);
  int ks = zz % KSPLIT;
  int e  = zz / KSPLIT;

  const unsigned short* A  = Ab + (size_t)e * CAP * KTOT;
  const unsigned short* Bt = Bb + (size_t)e * NDIM * KTOT;
  int bm = bx * 256, bn = by * 256;
  int kbase = ks * KLOC;

  int tid = threadIdx.x;
  int lane = tid & 63;
  int w = tid >> 6;
  int wr = w >> 2, wc = w & 3;
  int l15 = lane & 15, lq = lane >> 4;

  unsigned aoff[8], boff[4];
#pragma unroll
  for (int m = 0; m < 8; ++m)
    aoff[m] = swz((unsigned)((wr * 128 + m * 16 + l15) * 64 + lq * 16));
#pragma unroll
  for (int n = 0; n < 4; ++n)
    boff[n] = swz((unsigned)((wc * 64 + n * 16 + l15) * 64 + lq * 16));

  // staging sources (pre-swizzled global, linear LDS dest) — proven mapping
  const char *srcA0, *srcA1, *srcB0, *srcB1;
  unsigned dA0, dA1, dB0, dB1;
  {
    int idx0 = tid, idx1 = 512 + tid;
    int r0_ = idx0 >> 2, r1_ = idx1 >> 2;
    unsigned kb0 = ((unsigned)(idx0 & 3) * 16) ^ ((((unsigned)r0_ >> 1) & 3u) << 4);
    unsigned kb1 = ((unsigned)(idx1 & 3) * 16) ^ ((((unsigned)r1_ >> 1) & 3u) << 4);
    srcA0 = (const char*)(A  + (size_t)(bm + r0_) * KTOT + kbase) + kb0;
    srcA1 = (const char*)(A  + (size_t)(bm + r1_) * KTOT + kbase) + kb1;
    srcB0 = (const char*)(Bt + (size_t)(bn + r0_) * KTOT + kbase) + kb0;
    srcB1 = (const char*)(Bt + (size_t)(bn + r1_) * KTOT + kbase) + kb1;
    dA0 = (unsigned)idx0 * 16; dA1 = (unsigned)idx1 * 16;
    dB0 = 16384u + (unsigned)idx0 * 16; dB1 = 16384u + (unsigned)idx1 * 16;
  }

  // prologue: stage tiles 0,1,2
#pragma unroll
  for (int tt = 0; tt < 3; ++tt) {
    char* db = smem + tt * 32768;
    load_lds16(srcA0 + tt * 64, db + dA0);
    load_lds16(srcA1 + tt * 64, db + dA1);
    load_lds16(srcB0 + tt * 64, db + dB0);
    load_lds16(srcB1 + tt * 64, db + dB1);
  }
  srcA0 += 192; srcA1 += 192; srcB0 += 192; srcB1 += 192;
  asm volatile("s_waitcnt vmcnt(4)" ::: "memory");   // tiles 0,1 landed
  __builtin_amdgcn_s_barrier();

  f32x4 acc[8][4] = {};
  short8 afLo0[4], afLo1[4], bf0[4], bf1[4], af47[4];

  // pre-load tile0 subtile0 into set 0
#pragma unroll
  for (int j = 0; j < 4; ++j) afLo0[j] = *(const short8*)(smem + aoff[j]);
#pragma unroll
  for (int n = 0; n < 4; ++n) bf0[n]  = *(const short8*)(smem + 16384 + boff[n]);

#define TILE(T, CUR, NXT)                                                         \
  {                                                                               \
    const int t_ = (T);                                                           \
    const char* rb_ = smem + (t_ & 3) * 32768;                                    \
    _Pragma("unroll") for (int j = 0; j < 4; ++j)                                 \
        af47[j] = *(const short8*)(rb_ + aoff[4 + j]);                            \
    if (t_ + 3 < NT) {                                                            \
      char* db_ = smem + ((t_ + 3) & 3) * 32768;                                  \
      load_lds16(srcA0, db_ + dA0);                                               \
      load_lds16(srcA1, db_ + dA1);                                               \
    }                                                                             \
    __builtin_amdgcn_sched_barrier(0);                                            \
    __builtin_amdgcn_s_setprio(1);                                                \
    _Pragma("unroll") for (int m = 0; m < 4; ++m)                                 \
      _Pragma("unroll") for (int n = 0; n < 4; ++n)                               \
        acc[m][n] = __builtin_amdgcn_mfma_f32_16x16x32_bf16(                      \
            afLo##CUR[m], bf##CUR[n], acc[m][n], 0, 0, 0);                        \
    __builtin_amdgcn_s_setprio(0);                                                \
    __builtin_amdgcn_sched_barrier(0);                                            \
    if (t_ + 1 < NT) {                                                            \
      const char* rn_ = smem + ((t_ + 1) & 3) * 32768;                            \
      _Pragma("unroll") for (int j = 0; j < 4; ++j)                               \
          afLo##NXT[j] = *(const short8*)(rn_ + aoff[j]);                         \
      _Pragma("unroll") for (int n = 0; n < 4; ++n)                               \
          bf##NXT[n] = *(const short8*)(rn_ + 16384 + boff[n]);                   \
    }                                                                             \
    if (t_ + 3 < NT) {                                                            \
      char* db_ = smem + ((t_ + 3) & 3) * 32768;                                  \
      load_lds16(srcB0, db_ + dB0);                                               \
      load_lds16(srcB1, db_ + dB1);                                               \
    }                                                                             \
    __builtin_amdgcn_sched_barrier(0);                                            \
    __builtin_amdgcn_s_setprio(1);                                                \
    _Pragma("unroll") for (int m = 0; m < 4; ++m)                                 \
      _Pragma("unroll") for (int n = 0; n < 4; ++n)                               \
        acc[m + 4][n] = __builtin_amdgcn_mfma_f32_16x16x32_bf16(                  \
            af47[m], bf##CUR[n], acc[m + 4][n], 0, 0, 0);                         \
    __builtin_amdgcn_s_setprio(0);                                                \
    __builtin_amdgcn_sched_barrier(0);                                            \
    if (t_ + 3 < NT) asm volatile("s_waitcnt vmcnt(4)" ::: "memory");             \
    else             asm volatile("s_waitcnt vmcnt(0)" ::: "memory");             \
    __builtin_amdgcn_s_barrier();                                                 \
    srcA0 += 64; srcA1 += 64; srcB0 += 64; srcB1 += 64;                           \
  }

#pragma unroll 1
  for (int t = 0; t < NT; t += 2) {
    TILE(t, 0, 1);
    TILE(t + 1, 1, 0);
  }
#undef TILE

  // epilogue (proven C/D mapping)
  int r0 = bm + wr * 128 + lq * 4;
  int c0 = bn + wc * 64 + l15;
  if (OMODE == 1) {
    unsigned short* C = (unsigned short*)Cv + (size_t)e * CAP * NDIM;
#pragma unroll
    for (int m = 0; m < 8; ++m)
#pragma unroll
      for (int n = 0; n < 4; ++n)
#pragma unroll
        for (int j = 0; j < 4; ++j) {
          float v = acc[m][n][j];
          float y = 0.7978845608028654f * (v + 0.044715f * v * v * v);
          float g = v / (1.0f + __expf(-2.0f * y));   // tanh-gelu
          C[(size_t)(r0 + m * 16 + j) * NDIM + (c0 + n * 16)] = f2bf(g);
        }
  } else {
    unsigned short* C = (unsigned short*)Cv + ((size_t)ks * NE + e) * CAP * NDIM;
#pragma unroll
    for (int m = 0; m < 8; ++m)
#pragma unroll
      for (int n = 0; n < 4; ++n)
#pragma unroll
        for (int j = 0; j < 4; ++j)
          C[(size_t)(r0 + m * 16 + j) * NDIM + (c0 + n * 16)] = f2bf(acc[m][n][j]);
  }
}

// ---- scatter: out[t] = sum_k w[t,k]*(y0[e,r]+y1[e,r]) + bias ; y is bf16 partials ----
__global__ __launch_bounds__(128)
void scatter_kernel(const unsigned short* __restrict__ y, const int* __restrict__ te,
                    const int* __restrict__ rankA, const float* __restrict__ ew,
                    const float* __restrict__ bias, float* __restrict__ out) {
  int tk = blockIdx.x;
  int t = threadIdx.x;
  f32x4 a0 = *(const f32x4*)(bias + t * 8);
  f32x4 a1 = *(const f32x4*)(bias + t * 8 + 4);
#pragma unroll
  for (int k = 0; k < TOPK; ++k) {
    int a = tk * TOPK + k;
    int r = rankA[a];
    if (r < CAP) {
      float wgt = ew[a];
      size_t rowoff = ((size_t)te[a] * CAP + r) * HD + t * 8;
      u32x4 p0 = *(const u32x4*)(y + rowoff);
      u32x4 p1 = *(const u32x4*)(y + (size_t)NE * CAP * HD + rowoff);
#pragma unroll
      for (int j = 0; j < 2; ++j) {
        unsigned u0 = p0[j], u1 = p1[j];
        a0[2 * j]     += wgt * (__uint_as_float(u0 << 16) + __uint_as_float(u1 << 16));
        a0[2 * j + 1] += wgt * (__uint_as_float(u0 & 0xffff0000u) + __uint_as_float(u1 & 0xffff0000u));
      }
#pragma unroll
      for (int j = 0; j < 2; ++j) {
        unsigned u0 = p0[2 + j], u1 = p1[2 + j];
        a1[2 * j]     += wgt * (__uint_as_float(u0 << 16) + __uint_as_float(u1 << 16));
        a1[2 * j + 1] += wgt * (__uint_as_float(u0 & 0xffff0000u) + __uint_as_float(u1 & 0xffff0000u));
      }
    }
  }
  float* o = out + (size_t)tk * HD + t * 8;
  *(f32x4*)o = a0;
  *(f32x4*)(o + 4) = a1;
}

extern "C" void kernel_launch(void* const* d_in, const int* in_sizes, int n_in,
                              void* d_out, int out_size, void* d_ws, size_t ws_size,
                              hipStream_t stream) {
  const float* x    = (const float*)d_in[0];
  const float* ew   = (const float*)d_in[2];
  const int*   te   = (const int*)d_in[3];
  const float* w1   = (const float*)d_in[4];
  const float* w2   = (const float*)d_in[5];
  const float* bias = (const float*)d_in[6];
  float* out = (float*)d_out;

  unsigned short* w1t  = (unsigned short*)d_ws;                 // [E][F][H] bf16  64MB
  unsigned short* w2t  = w1t + (size_t)NE * HD * FD;            // [E][H][F] bf16  64MB
  unsigned short* bufg = w2t + (size_t)NE * HD * FD;            // [E][CAP][H]     16MB
  unsigned short* hbuf = bufg + (size_t)NE * CAP * HD;          // [E][CAP][F]     64MB
  unsigned short* ybuf = w1t;                                   // alias (w1t dead): [2][E][CAP][H] bf16 32MB
  int* rankA  = (int*)(hbuf + (size_t)NE * CAP * FD);
  int* srcTok = rankA + NASSIGN;
  int* counts = srcTok + NE * CAP;

  transpose_convert<<<dim3(FD / 64, HD / 64, NE), 256, 0, stream>>>(w1, w1t, HD, FD);
  transpose_convert<<<dim3(HD / 64, FD / 64, NE), 256, 0, stream>>>(w2, w2t, FD, HD);
  routing_kernel<<<1, 1024, 0, stream>>>(te, rankA, srcTok, counts);
  gather_kernel<<<NE * CAP, 128, 0, stream>>>(x, srcTok, counts, bufg);
  // GEMM1: [CAP,HD] @ [FD,HD]^T -> gelu -> bf16 hbuf ; 512 blocks
  gemm256<HD, FD, 1, 1><<<512, 512, 0, stream>>>(bufg, w1t, (void*)hbuf);
  // GEMM2: [CAP,FD] @ [HD,FD]^T -> bf16 partials (split-K=2) ; 256 blocks
  gemm256<FD, HD, 2, 2><<<256, 512, 0, stream>>>(hbuf, w2t, (void*)ybuf);
  scatter_kernel<<<NTOK, 128, 0, stream>>>(ybuf, te, rankA, ew, bias, out);
}